// Round 1
// baseline (792.739 us; speedup 1.0000x reference)
//
#include <hip/hip_runtime.h>

using u16 = unsigned short;
typedef short short8 __attribute__((ext_vector_type(8)));
typedef float f32x4 __attribute__((ext_vector_type(4)));

#define T_TOK 100352

__device__ __forceinline__ float bf2f(u16 u) {
    return __uint_as_float(((unsigned int)u) << 16);
}
__device__ __forceinline__ u16 f2bf(float f) {
    unsigned int u = __float_as_uint(f);
    u += 0x7fffu + ((u >> 16) & 1u);   // round-to-nearest-even
    return (u16)(u >> 16);
}

// ---------------------------------------------------------------- setup ----
__global__ __launch_bounds__(256) void cvt_bf16_k(const float* __restrict__ src,
                                                  u16* __restrict__ dst, int n) {
    int i = blockIdx.x * 256 + threadIdx.x;
    int stride = gridDim.x * 256;
    for (; i < n; i += stride) dst[i] = f2bf(src[i]);
}

// bias table: [half(2)][wtype(4)][head(4)][n(49)][m(49)] f32
// wtype = (wi==31)*2 + (wj==31)
__global__ __launch_bounds__(256) void bias_tbl_k(const float* __restrict__ rpb0,
                                                  const float* __restrict__ rpb1,
                                                  float* __restrict__ tbl) {
    int id = blockIdx.x;               // half*16 + wtype*4 + h
    int hsel = id >> 4, wtype = (id >> 2) & 3, h = id & 3;
    const float* rpb = hsel ? rpb1 : rpb0;
    int redge = wtype >> 1, cedge = wtype & 1;
    float* o = tbl + (size_t)id * 2401;
    for (int i = threadIdx.x; i < 2401; i += 256) {
        int n = i / 49, m = i - n * 49;
        int rn = n / 7, cn = n - rn * 7, rm = m / 7, cm = m - rm * 7;
        int rpi = (rn - rm + 6) * 13 + (cn - cm + 6);
        float v = rpb[rpi * 4 + h];
        // shifted-window mask (regions only differ on edge windows)
        int grn = redge ? (rn < 4 ? 1 : 2) : 0;
        int grm = redge ? (rm < 4 ? 1 : 2) : 0;
        int gcn = cedge ? (cn < 4 ? 1 : 2) : 0;
        int gcm = cedge ? (cm < 4 ? 1 : 2) : 0;
        if ((grn * 3 + gcn) != (grm * 3 + gcm)) v += -100.0f;
        // physical cone mask (derived allowed sets, fp32-borderline (5,6) IN)
        int dr = rn - rm, dc = cn - cm;
        bool ok;
        if (n == m) ok = true;
        else if (hsel == 0)
            ok = (dc == 1 && dr == 1) || (dc == 2 && dr == 2) ||
                 (dc == 3 && (dr == 3 || dr == 4)) ||
                 (dc == 4 && (dr == 4 || dr == 5)) ||
                 (dc == 5 && (dr == 5 || dr == 6)) ||
                 (dc == 6 && (dr == 5 || dr == 6));
        else
            ok = (dr == -1 && dc >= 3 && dc <= 6) || (dr == -2 && dc == 6);
        if (!ok) v += -100.0f;
        o[i] = v;
    }
}

// ------------------------------------------------------------ layernorms ----
// LN1 + roll(-3,-3) + window partition -> bf16 windowed layout, both halves
__global__ __launch_bounds__(256) void ln1_k(const float* __restrict__ x,
                                             const float* __restrict__ g,
                                             const float* __restrict__ b,
                                             u16* __restrict__ xw) {
    int t = blockIdx.x * 4 + (threadIdx.x >> 6);
    int lane = threadIdx.x & 63;
    const float4 v = *(const float4*)(x + (size_t)t * 256 + lane * 4);
    float s = v.x + v.y + v.z + v.w;
    float s2 = v.x * v.x + v.y * v.y + v.z * v.z + v.w * v.w;
#pragma unroll
    for (int off = 1; off < 64; off <<= 1) {
        s += __shfl_xor(s, off);
        s2 += __shfl_xor(s2, off);
    }
    float mean = s * (1.0f / 256.0f);
    float var = s2 * (1.0f / 256.0f) - mean * mean;
    float rstd = 1.0f / sqrtf(var + 1e-5f);

    int bb = (t >= 50176) ? 1 : 0;
    int l = t - bb * 50176;
    int rr = l / 224, cc = l - rr * 224;
    int r2 = rr - 3; if (r2 < 0) r2 += 224;
    int c2 = cc - 3; if (c2 < 0) c2 += 224;
    int wi = r2 / 7, lr = r2 - wi * 7;
    int wj = c2 / 7, lc = c2 - wj * 7;
    size_t mIdx = (size_t)(((bb << 10) + wi * 32 + wj) * 49 + lr * 7 + lc);

    int ch = lane * 4;
    int hsel = ch >> 7, colb = ch & 127;
    const float4 gv = *(const float4*)(g + ch);
    const float4 bv = *(const float4*)(b + ch);
    union { uint2 u; u16 s4[4]; } pk;
    pk.s4[0] = f2bf((v.x - mean) * rstd * gv.x + bv.x);
    pk.s4[1] = f2bf((v.y - mean) * rstd * gv.y + bv.y);
    pk.s4[2] = f2bf((v.z - mean) * rstd * gv.z + bv.z);
    pk.s4[3] = f2bf((v.w - mean) * rstd * gv.w + bv.w);
    *(uint2*)(xw + (size_t)hsel * T_TOK * 128 + mIdx * 128 + colb) = pk.u;
}

// LN2: plain token order -> bf16
__global__ __launch_bounds__(256) void ln2_k(const float* __restrict__ x,
                                             const float* __restrict__ g,
                                             const float* __restrict__ b,
                                             u16* __restrict__ h) {
    int t = blockIdx.x * 4 + (threadIdx.x >> 6);
    int lane = threadIdx.x & 63;
    const float4 v = *(const float4*)(x + (size_t)t * 256 + lane * 4);
    float s = v.x + v.y + v.z + v.w;
    float s2 = v.x * v.x + v.y * v.y + v.z * v.z + v.w * v.w;
#pragma unroll
    for (int off = 1; off < 64; off <<= 1) {
        s += __shfl_xor(s, off);
        s2 += __shfl_xor(s2, off);
    }
    float mean = s * (1.0f / 256.0f);
    float var = s2 * (1.0f / 256.0f) - mean * mean;
    float rstd = 1.0f / sqrtf(var + 1e-5f);
    int ch = lane * 4;
    const float4 gv = *(const float4*)(g + ch);
    const float4 bv = *(const float4*)(b + ch);
    union { uint2 u; u16 s4[4]; } pk;
    pk.s4[0] = f2bf((v.x - mean) * rstd * gv.x + bv.x);
    pk.s4[1] = f2bf((v.y - mean) * rstd * gv.y + bv.y);
    pk.s4[2] = f2bf((v.z - mean) * rstd * gv.z + bv.z);
    pk.s4[3] = f2bf((v.w - mean) * rstd * gv.w + bv.w);
    *(uint2*)(h + (size_t)t * 256 + ch) = pk.u;
}

// ---------------------------------------------------------------- GEMM ----
// C[M x N] = A[M x K] * W[N x K]^T + bias, bf16 in, fp32 accum (MFMA 16x16x32)
// BM=BN=128, BK=64, 4 waves of 64x64, XOR-swizzled LDS (T2).
// EPI: 0=qkv(store bf16, scale q cols), 1=proj(window-reverse+roll+residual->x2 f32),
//      2=fc1(gelu->bf16), 3=fc2(+bias+residual->f32 out)
template <int EPI>
__global__ __launch_bounds__(256) void gemm_k(const u16* __restrict__ A,
                                              const u16* __restrict__ W,
                                              const float* __restrict__ bias,
                                              const float* __restrict__ resid,
                                              void* __restrict__ outp,
                                              int K, int hsel) {
    __shared__ u16 As[128][64];
    __shared__ u16 Bs[128][64];
    const int tid = threadIdx.x;
    const int lane = tid & 63;
    const int wave = tid >> 6;
    const int wr = wave >> 1, wc = wave & 1;
    const int bm = blockIdx.x, bn = blockIdx.y;
    const int r = lane & 15, kg = lane >> 4;

    f32x4 acc[4][4] = {};

    for (int kt = 0; kt < K; kt += 64) {
#pragma unroll
        for (int i = 0; i < 4; ++i) {
            int idx = tid + i * 256;   // 0..1023 : 128 rows x 8 16B-chunks
            int row = idx >> 3, cb = idx & 7;
            uint4 va = *(const uint4*)(A + (size_t)(bm * 128 + row) * K + kt + cb * 8);
            *(uint4*)(&As[row][(cb ^ (row & 7)) * 8]) = va;
            uint4 vb = *(const uint4*)(W + (size_t)(bn * 128 + row) * K + kt + cb * 8);
            *(uint4*)(&Bs[row][(cb ^ (row & 7)) * 8]) = vb;
        }
        __syncthreads();
#pragma unroll
        for (int ks = 0; ks < 2; ++ks) {
            short8 fa[4], fb[4];
#pragma unroll
            for (int mf = 0; mf < 4; ++mf) {
                int ra = wr * 64 + mf * 16 + r;
                fa[mf] = *(const short8*)(&As[ra][((ks * 4 + kg) ^ (ra & 7)) * 8]);
            }
#pragma unroll
            for (int nf = 0; nf < 4; ++nf) {
                int rb = wc * 64 + nf * 16 + r;
                fb[nf] = *(const short8*)(&Bs[rb][((ks * 4 + kg) ^ (rb & 7)) * 8]);
            }
#pragma unroll
            for (int mf = 0; mf < 4; ++mf)
#pragma unroll
                for (int nf = 0; nf < 4; ++nf)
                    acc[mf][nf] = __builtin_amdgcn_mfma_f32_16x16x32_bf16(
                        fa[mf], fb[nf], acc[mf][nf], 0, 0, 0);
        }
        __syncthreads();
    }

#pragma unroll
    for (int mf = 0; mf < 4; ++mf) {
#pragma unroll
        for (int nf = 0; nf < 4; ++nf) {
#pragma unroll
            for (int j = 0; j < 4; ++j) {
                int row = wr * 64 + mf * 16 + kg * 4 + j;
                int col = wc * 64 + nf * 16 + r;
                int gm = bm * 128 + row;
                int gn = bn * 128 + col;
                float v = acc[mf][nf][j] + bias[gn];
                if (EPI == 0) {
                    if (gn < 128) v *= 0.17677669529663687f;  // 1/sqrt(32) on q
                    ((u16*)outp)[(size_t)gm * 384 + gn] = f2bf(v);
                } else if (EPI == 1) {
                    int win = gm / 49, n = gm - win * 49;
                    int bb = win >> 10, w = win & 1023, wi = w >> 5, wj = w & 31;
                    int lr = n / 7, lc = n - lr * 7;
                    int R = wi * 7 + lr + 3;  if (R >= 224) R -= 224;
                    int Cc = wj * 7 + lc + 3; if (Cc >= 224) Cc -= 224;
                    size_t o = ((size_t)bb * 50176 + (size_t)R * 224 + Cc) * 256 +
                               hsel * 128 + gn;
                    ((float*)outp)[o] = resid[o] + v;
                } else if (EPI == 2) {
                    float gl = 0.5f * v * (1.0f + erff(v * 0.70710678118654752f));
                    ((u16*)outp)[(size_t)gm * 1024 + gn] = f2bf(gl);
                } else {
                    size_t o = (size_t)gm * 256 + gn;
                    ((float*)outp)[o] = v + resid[o];
                }
            }
        }
    }
}

// ------------------------------------------------------------ attention ----
// block = (half, window); wave = head; lane = q-row. k/v staged fp32 in LDS
// (broadcast reads, conflict-free). No-max online softmax (logits tiny;
// mask -100 -> exp underflows to 0, matching the reference numerically).
__global__ __launch_bounds__(256) void attn_k(const u16* __restrict__ qkv,
                                              const float* __restrict__ btbl,
                                              u16* __restrict__ attnout) {
    int bid = blockIdx.x;
    int hsel = bid >> 11;
    int win = bid & 2047;
    int w = win & 1023;
    int wi = w >> 5, wj = w & 31;
    int wtype = ((wi == 31) ? 2 : 0) + ((wj == 31) ? 1 : 0);
    const u16* src = qkv + (size_t)hsel * T_TOK * 384 + (size_t)win * 49 * 384;

    __shared__ float kv[49][256];  // [m][0..127]=k, [128..255]=v
    int tid = threadIdx.x;
    for (int c = tid; c < 1568; c += 256) {  // 49*256/8 chunks
        int row = c >> 5, cc = (c & 31) * 8;
        uint4 u = *(const uint4*)(src + row * 384 + 128 + cc);
        const u16* us = (const u16*)&u;
#pragma unroll
        for (int j = 0; j < 8; ++j) kv[row][cc + j] = bf2f(us[j]);
    }

    int h = tid >> 6, n = tid & 63;
    float q[32];
    bool act = (n < 49);
    if (act) {
        const u16* qp = src + n * 384 + h * 32;
#pragma unroll
        for (int g8 = 0; g8 < 4; ++g8) {
            uint4 u = *(const uint4*)(qp + g8 * 8);
            const u16* us = (const u16*)&u;
#pragma unroll
            for (int j = 0; j < 8; ++j) q[g8 * 8 + j] = bf2f(us[j]);
        }
    }
    __syncthreads();
    if (!act) return;

    const float* bias = btbl + ((size_t)((hsel * 4 + wtype) * 4 + h)) * 2401 + n * 49;
    float o[32];
#pragma unroll
    for (int d = 0; d < 32; ++d) o[d] = 0.0f;
    float sum = 0.0f;

    for (int m = 0; m < 49; ++m) {
        const float4* kr = (const float4*)&kv[m][h * 32];
        float dot = 0.0f;
#pragma unroll
        for (int j = 0; j < 8; ++j) {
            float4 kk = kr[j];
            dot += q[j * 4 + 0] * kk.x + q[j * 4 + 1] * kk.y +
                   q[j * 4 + 2] * kk.z + q[j * 4 + 3] * kk.w;
        }
        float p = __expf(dot + bias[m]);
        sum += p;
        const float4* vr = (const float4*)&kv[m][128 + h * 32];
#pragma unroll
        for (int j = 0; j < 8; ++j) {
            float4 vv = vr[j];
            o[j * 4 + 0] += p * vv.x;
            o[j * 4 + 1] += p * vv.y;
            o[j * 4 + 2] += p * vv.z;
            o[j * 4 + 3] += p * vv.w;
        }
    }
    float inv = 1.0f / sum;
    u16* op = attnout + (size_t)hsel * T_TOK * 128 + (size_t)(win * 49 + n) * 128 + h * 32;
#pragma unroll
    for (int g8 = 0; g8 < 4; ++g8) {
        union { uint4 u; u16 s[8]; } pk;
#pragma unroll
        for (int j = 0; j < 8; ++j) pk.s[j] = f2bf(o[g8 * 8 + j] * inv);
        *(uint4*)(op + g8 * 8) = pk.u;
    }
}

// ---------------------------------------------------------------- launch ----
extern "C" void kernel_launch(void* const* d_in, const int* in_sizes, int n_in,
                              void* d_out, int out_size, void* d_ws, size_t ws_size,
                              hipStream_t stream) {
    (void)in_sizes; (void)n_in; (void)out_size; (void)ws_size;
    const float* x      = (const float*)d_in[0];
    const float* n1g    = (const float*)d_in[3];
    const float* n1b    = (const float*)d_in[4];
    const float* n2g    = (const float*)d_in[5];
    const float* n2b    = (const float*)d_in[6];
    const float* qkvw1  = (const float*)d_in[7];
    const float* qkvb1  = (const float*)d_in[8];
    const float* projw1 = (const float*)d_in[9];
    const float* projb1 = (const float*)d_in[10];
    const float* rpb1   = (const float*)d_in[11];
    const float* qkvw2  = (const float*)d_in[12];
    const float* qkvb2  = (const float*)d_in[13];
    const float* projw2 = (const float*)d_in[14];
    const float* projb2 = (const float*)d_in[15];
    const float* rpb2   = (const float*)d_in[16];
    const float* fc1w   = (const float*)d_in[17];
    const float* fc1b   = (const float*)d_in[18];
    const float* fc2w   = (const float*)d_in[19];
    const float* fc2b   = (const float*)d_in[20];
    float* out = (float*)d_out;

    // ---- workspace layout (total 361,279,616 B) ----
    // [0, 154140672)        qkv bf16 (2 halves x T x 384)     } reused later as
    // [154140672, 205520896) xw / attnout bf16 (2 x T x 128)  } hidden (T x 1024)
    // [205520896, 308281344) x2 f32 (T x 256)
    // [308281344, 359661568) h bf16 (T x 256)
    // [359661568, 359968896) bias tables f32
    // [359968896, ...)       bf16 weights
    char* ws = (char*)d_ws;
    u16* qkv_buf = (u16*)ws;
    u16* xw      = (u16*)(ws + 154140672LL);
    u16* hidden  = (u16*)ws;
    float* x2    = (float*)(ws + 205520896LL);
    u16* hbuf    = (u16*)(ws + 308281344LL);
    float* btbl  = (float*)(ws + 359661568LL);
    u16* wbf     = (u16*)(ws + 359968896LL);
    u16* qw0 = wbf;
    u16* qw1 = wbf + 49152;
    u16* pw0 = wbf + 98304;
    u16* pw1 = wbf + 114688;
    u16* f1w = wbf + 131072;
    u16* f2w = wbf + 393216;

    cvt_bf16_k<<<48, 256, 0, stream>>>(qkvw1, qw0, 49152);
    cvt_bf16_k<<<48, 256, 0, stream>>>(qkvw2, qw1, 49152);
    cvt_bf16_k<<<16, 256, 0, stream>>>(projw1, pw0, 16384);
    cvt_bf16_k<<<16, 256, 0, stream>>>(projw2, pw1, 16384);
    cvt_bf16_k<<<256, 256, 0, stream>>>(fc1w, f1w, 262144);
    cvt_bf16_k<<<256, 256, 0, stream>>>(fc2w, f2w, 262144);
    bias_tbl_k<<<32, 256, 0, stream>>>(rpb1, rpb2, btbl);

    ln1_k<<<25088, 256, 0, stream>>>(x, n1g, n1b, xw);

    gemm_k<0><<<dim3(784, 3), 256, 0, stream>>>(xw, qw0, qkvb1, nullptr,
                                                qkv_buf, 128, 0);
    gemm_k<0><<<dim3(784, 3), 256, 0, stream>>>(xw + (size_t)T_TOK * 128, qw1, qkvb2,
                                                nullptr, qkv_buf + (size_t)T_TOK * 384,
                                                128, 1);

    attn_k<<<4096, 256, 0, stream>>>(qkv_buf, btbl, xw);  // attnout overwrites xw

    gemm_k<1><<<dim3(784, 1), 256, 0, stream>>>(xw, pw0, projb1, x, x2, 128, 0);
    gemm_k<1><<<dim3(784, 1), 256, 0, stream>>>(xw + (size_t)T_TOK * 128, pw1, projb2,
                                                x, x2, 128, 1);

    ln2_k<<<25088, 256, 0, stream>>>(x2, n2g, n2b, hbuf);
    gemm_k<2><<<dim3(784, 8), 256, 0, stream>>>(hbuf, f1w, fc1b, nullptr,
                                                hidden, 256, 0);
    gemm_k<3><<<dim3(784, 2), 256, 0, stream>>>(hidden, f2w, fc2b, x2, out, 1024, 0);
}